// Round 1
// baseline (695.986 us; speedup 1.0000x reference)
//
#include <hip/hip_runtime.h>

// Reference collapse analysis:
//   x[:,None,:] -> conv input (N=8192, W=1, C=16384): spatial length 1.
//   Conv k=2, dilation d, SAME: pad_total=d, pad_low=d//2; taps at {0,d},
//   real sample at d//2.
//     d=1  : tap0 hits the sample -> c1[b] = dot(x[b], w1[0,:,0]) + b1
//     d=4,8,32,128: both taps hit zero padding -> c_i = b_i (constant)
//   => s[b] = c1[b] + b2+b3+b4+b5  (leaky-ReLUs are dead code)
//   => out[b,j] = s[b]*wd[0,j] + bd[j]
// Pure memory-bound: stream 512 MiB of x once. Roofline ~81 us @ 6.3 TB/s.

constexpr int L    = 16384;
constexpr int OUTD = 128;
constexpr int ROWS_PER_BLOCK = 4;   // 4 waves of 64, one row per wave

__global__ __launch_bounds__(256)
void audio_collapse_kernel(const float* __restrict__ x,    // (B, L)
                           const float* __restrict__ w1,   // (2, L, 1); use first L
                           const float* __restrict__ b1,
                           const float* __restrict__ b2,
                           const float* __restrict__ b3,
                           const float* __restrict__ b4,
                           const float* __restrict__ b5,
                           const float* __restrict__ wd,   // (1, 128)
                           const float* __restrict__ bd,   // (128,)
                           float* __restrict__ out,        // (B, 128)
                           int B)
{
    const int wave = threadIdx.x >> 6;
    const int lane = threadIdx.x & 63;
    const int row  = blockIdx.x * ROWS_PER_BLOCK + wave;
    if (row >= B) return;

    const float4* __restrict__ xr = (const float4*)(x + (size_t)row * L);
    const float4* __restrict__ wr = (const float4*)(w1);  // w1[0,:,0] is contiguous

    // 16384 floats = 4096 float4; 64 lanes -> 64 iterations per lane.
    // Two accumulators for a little ILP on the FP adds.
    float acc0 = 0.f, acc1 = 0.f;
    #pragma unroll 4
    for (int i = lane; i < L / 4; i += 128) {
        float4 xv = xr[i];
        float4 wv = wr[i];
        float4 xv2 = xr[i + 64];
        float4 wv2 = wr[i + 64];
        acc0 += xv.x * wv.x + xv.y * wv.y + xv.z * wv.z + xv.w * wv.w;
        acc1 += xv2.x * wv2.x + xv2.y * wv2.y + xv2.z * wv2.z + xv2.w * wv2.w;
    }
    float acc = acc0 + acc1;

    // Butterfly reduce across the 64-lane wave; all lanes end with the sum.
    #pragma unroll
    for (int off = 32; off > 0; off >>= 1)
        acc += __shfl_xor(acc, off, 64);

    const float y = acc + b1[0] + b2[0] + b3[0] + b4[0] + b5[0];

    // Epilogue: out[row, j] = y * wd[j] + bd[j]; 128 outputs, 2 per lane.
    float* __restrict__ orow = out + (size_t)row * OUTD;
    #pragma unroll
    for (int j = lane; j < OUTD; j += 64)
        orow[j] = fmaf(y, wd[j], bd[j]);
}

extern "C" void kernel_launch(void* const* d_in, const int* in_sizes, int n_in,
                              void* d_out, int out_size, void* d_ws, size_t ws_size,
                              hipStream_t stream) {
    const float* x  = (const float*)d_in[0];
    const float* w1 = (const float*)d_in[1];
    const float* b1 = (const float*)d_in[2];
    const float* b2 = (const float*)d_in[4];
    const float* b3 = (const float*)d_in[6];
    const float* b4 = (const float*)d_in[8];
    const float* b5 = (const float*)d_in[10];
    const float* wd = (const float*)d_in[11];
    const float* bd = (const float*)d_in[12];
    float* out = (float*)d_out;

    const int B = in_sizes[0] / L;   // 8192
    const int grid = (B + ROWS_PER_BLOCK - 1) / ROWS_PER_BLOCK;

    audio_collapse_kernel<<<grid, 256, 0, stream>>>(
        x, w1, b1, b2, b3, b4, b5, wd, bd, out, B);
}

// Round 3
// 665.853 us; speedup vs baseline: 1.0453x; 1.0453x over previous
//
#include <hip/hip_runtime.h>

// Reference collapse analysis (verified round 1, absmax 0.03 vs thr 0.27):
//   x[:,None,:] -> conv input (N=8192, W=1, C=16384): spatial length 1.
//   Conv k=2, dilation d, SAME: taps at {0,d}, sample at d//2.
//     d=1: c1[b] = dot(x[b], w1[0,:,0]) + b1;  d=4,8,32,128: c_i = b_i (const).
//   => out[b,j] = (dot(x[b], w1[0]) + b1+b2+b3+b4+b5) * wd[j] + bd[j]
// Memory-bound: stream 512 MiB of x once. Floor ~85 us @ 6.3 TB/s.
//
// Round-3: same as round-2 plan, but nontemporal builtins need native Clang
// vector types (ext_vector_type), not HIP_vector_type<float,4>.

constexpr int L    = 16384;
constexpr int OUTD = 128;
constexpr int ROWS_PER_BLOCK = 4;   // 4 waves of 64, one row per wave

typedef float fx4 __attribute__((ext_vector_type(4)));

__global__ __launch_bounds__(256)
void audio_collapse_kernel(const float* __restrict__ x,    // (B, L)
                           const float* __restrict__ w1,   // (2, L, 1); first L used
                           const float* __restrict__ b1,
                           const float* __restrict__ b2,
                           const float* __restrict__ b3,
                           const float* __restrict__ b4,
                           const float* __restrict__ b5,
                           const float* __restrict__ wd,   // (1, 128)
                           const float* __restrict__ bd,   // (128,)
                           float* __restrict__ out,        // (B, 128)
                           int B)
{
    const int wave = threadIdx.x >> 6;
    const int lane = threadIdx.x & 63;
    const int row  = blockIdx.x * ROWS_PER_BLOCK + wave;
    if (row >= B) return;

    const fx4* __restrict__ xr = (const fx4*)(x + (size_t)row * L);
    const fx4* __restrict__ wr = (const fx4*)(w1);  // w1[0,:,0] contiguous

    // 4096 float4 per row; 64 lanes x stride 256 x 4 vectors -> 16 outer steps.
    float acc0 = 0.f, acc1 = 0.f, acc2 = 0.f, acc3 = 0.f;
    #pragma unroll
    for (int k = 0; k < L / 4 / 256; ++k) {
        const int base = k * 256 + lane;
        // Issue all 8 loads before any FMA: 4 nt x-loads (HBM) + 4 w-loads (L2).
        fx4 xv0 = __builtin_nontemporal_load(&xr[base]);
        fx4 xv1 = __builtin_nontemporal_load(&xr[base +  64]);
        fx4 xv2 = __builtin_nontemporal_load(&xr[base + 128]);
        fx4 xv3 = __builtin_nontemporal_load(&xr[base + 192]);
        fx4 wv0 = wr[base];
        fx4 wv1 = wr[base +  64];
        fx4 wv2 = wr[base + 128];
        fx4 wv3 = wr[base + 192];
        acc0 += xv0.x * wv0.x + xv0.y * wv0.y + xv0.z * wv0.z + xv0.w * wv0.w;
        acc1 += xv1.x * wv1.x + xv1.y * wv1.y + xv1.z * wv1.z + xv1.w * wv1.w;
        acc2 += xv2.x * wv2.x + xv2.y * wv2.y + xv2.z * wv2.z + xv2.w * wv2.w;
        acc3 += xv3.x * wv3.x + xv3.y * wv3.y + xv3.z * wv3.z + xv3.w * wv3.w;
    }
    float acc = (acc0 + acc1) + (acc2 + acc3);

    // Butterfly reduce across the 64-lane wave; all lanes end with the sum.
    #pragma unroll
    for (int off = 32; off > 0; off >>= 1)
        acc += __shfl_xor(acc, off, 64);

    const float y = acc + b1[0] + b2[0] + b3[0] + b4[0] + b5[0];

    // Epilogue: out[row, j] = y * wd[j] + bd[j]; 128 outputs, 2 per lane.
    float* __restrict__ orow = out + (size_t)row * OUTD;
    #pragma unroll
    for (int j = lane; j < OUTD; j += 64)
        __builtin_nontemporal_store(fmaf(y, wd[j], bd[j]), &orow[j]);
}

extern "C" void kernel_launch(void* const* d_in, const int* in_sizes, int n_in,
                              void* d_out, int out_size, void* d_ws, size_t ws_size,
                              hipStream_t stream) {
    const float* x  = (const float*)d_in[0];
    const float* w1 = (const float*)d_in[1];
    const float* b1 = (const float*)d_in[2];
    const float* b2 = (const float*)d_in[4];
    const float* b3 = (const float*)d_in[6];
    const float* b4 = (const float*)d_in[8];
    const float* b5 = (const float*)d_in[10];
    const float* wd = (const float*)d_in[11];
    const float* bd = (const float*)d_in[12];
    float* out = (float*)d_out;

    const int B = in_sizes[0] / L;   // 8192
    const int grid = (B + ROWS_PER_BLOCK - 1) / ROWS_PER_BLOCK;

    audio_collapse_kernel<<<grid, 256, 0, stream>>>(
        x, w1, b1, b2, b3, b4, b5, wd, bd, out, B);
}